// Round 8
// baseline (129.997 us; speedup 1.0000x reference)
//
#include <hip/hip_runtime.h>
#include <stdint.h>

// Sizes: h (8,1024,512) f32, s (8,128,1024)->(1024,1024) f32,
//        Wh (512,128), Ws (1024,128), b,v (128,), out (8,128,1024) f32.
//
// Identity 1: tanh(ps+ph) = 1 - 2/(Eps*Eph + 1),
//   Eps = exp2(2*log2e*ps), Eph = exp2(2*log2e*ph) precomputed in GEMM
//   epilogue (1.18M exp2 instead of 134M in the attn loop).
// Identity 2: sum_a v_a/w_a over 4 terms shares ONE rcp via rational-sum
//   pairwise merging (14 VALU + 1 rcp per 4 terms).
// Identity 3: merge VALU packed as v_pk_fma_f32 — this round packed over
//   the Y-PAIR (Eps pairs, Eph splatted), since each thread owns one x.
// R8 (fixes R7's OOB): attn = 256 blocks x 1024 thr; thread t owns x=t
//   and 4 y-rows. Halves Eph L2 re-reads (256->128 MB) at 4 waves/SIMD.
//   R7 crashed because it kept x-pair indexing (float2 writes past the
//   1024-float row / end of d_out) — shape itself was never tested.

typedef float  f32x4  __attribute__((ext_vector_type(4)));
typedef float  f32x2  __attribute__((ext_vector_type(2)));
typedef __bf16 bf16x8 __attribute__((ext_vector_type(8)));

#define LOG2E     1.4426950408889634f
#define TWO_LOG2E 2.8853900817779268f
#define FMA2(a, b, c) __builtin_elementwise_fma((a), (b), (c))

// ------------------------------------------------- weight transpose + cast
__global__ void __launch_bounds__(256) transpose_cast(
    const float* __restrict__ Wh, const float* __restrict__ Ws,
    __bf16* __restrict__ WhT, __bf16* __restrict__ WsT)
{
    int bid = blockIdx.x;  // 0..7 -> Wh tiles, 8..23 -> Ws tiles
    const float* src; __bf16* dst; int K, c0;
    if (bid < 8) { src = Wh; dst = WhT; K = 512;  c0 = bid * 64; }
    else         { src = Ws; dst = WsT; K = 1024; c0 = (bid - 8) * 64; }
    __shared__ float tile[64][129];
    int t = threadIdx.x;
    for (int i = 0; i < 8192; i += 256) {
        int idx = i + t;
        int r = idx >> 7, col = idx & 127;              // 64 rows(c) x 128 cols(a)
        tile[r][col] = src[(size_t)(c0 + r) * 128 + col];
    }
    __syncthreads();
    for (int i = 0; i < 8192; i += 256) {
        int idx = i + t;
        int a = idx >> 6, cc = idx & 63;                // 128 rows(a) x 64 cols(c)
        dst[(size_t)a * K + c0 + cc] = (__bf16)tile[cc][a];
    }
}

// --------------------------------------- barrier-free register MFMA GEMM
// blocks 0..255 : Eph  (A=WhT 128x512,  B=h f32,  32 cols/block)
// blocks 256..287: Eps (A=WsT 128x1024, B=s f32,  32 cols/block, +bias)
// wave w: m-half = (w&1)*64 (4 m-tiles), col-group = (w>>1)*16.
__global__ void __launch_bounds__(256) gemm_fused(
    const __bf16* __restrict__ WhT, const __bf16* __restrict__ WsT,
    const float* __restrict__ h, const float* __restrict__ s,
    float* __restrict__ Eph, float* __restrict__ Eps,
    const float* __restrict__ bias)
{
    int bid = blockIdx.x;
    int tid = threadIdx.x, lane = tid & 63, w = tid >> 6;
    int mbase = (w & 1) * 64;
    const __bf16* A; const float* B; float* Cp; int K; bool isPs;
    int colg;
    if (bid < 256) {
        isPs = false; A = WhT; B = h; K = 512;
        colg = bid * 32 + (w >> 1) * 16;
        int n = colg >> 10, x = colg & 1023;
        Cp = Eph + (size_t)n * 131072 + x;     // + m*1024 + col in epilogue
    } else {
        isPs = true; A = WsT; B = s; K = 1024;
        colg = (bid - 256) * 32 + (w >> 1) * 16;
        Cp = Eps + colg;
    }
    int q = lane >> 4;
    const float*  Bp = B + (size_t)(colg + (lane & 15)) * K + q * 8;
    const __bf16* Ap = A + (size_t)(mbase + (lane & 15)) * K + q * 8;

    f32x4 acc[4] = {};
    float4 b0 = *(const float4*)(Bp);
    float4 b1 = *(const float4*)(Bp + 4);
    bf16x8 a_[4];
    #pragma unroll
    for (int i = 0; i < 4; ++i) a_[i] = *(const bf16x8*)(Ap + (size_t)i * 16 * K);

    for (int k0 = 0; k0 < K; k0 += 32) {
        int kn = k0 + 32; if (kn > K - 32) kn = K - 32;   // clamped (dup last)
        float4 nb0 = *(const float4*)(Bp + kn);
        float4 nb1 = *(const float4*)(Bp + kn + 4);
        bf16x8 na[4];
        #pragma unroll
        for (int i = 0; i < 4; ++i)
            na[i] = *(const bf16x8*)(Ap + (size_t)i * 16 * K + kn);
        bf16x8 bf;
        bf[0] = (__bf16)b0.x; bf[1] = (__bf16)b0.y;
        bf[2] = (__bf16)b0.z; bf[3] = (__bf16)b0.w;
        bf[4] = (__bf16)b1.x; bf[5] = (__bf16)b1.y;
        bf[6] = (__bf16)b1.z; bf[7] = (__bf16)b1.w;
        #pragma unroll
        for (int i = 0; i < 4; ++i)
            acc[i] = __builtin_amdgcn_mfma_f32_16x16x32_bf16(a_[i], bf, acc[i], 0, 0, 0);
        b0 = nb0; b1 = nb1;
        #pragma unroll
        for (int i = 0; i < 4; ++i) a_[i] = na[i];
    }

    // C/D layout: col=lane&15, row(within 16-tile)=q*4+r  (m89-verified)
    int col = lane & 15;
    #pragma unroll
    for (int i = 0; i < 4; ++i) {
        #pragma unroll
        for (int r = 0; r < 4; ++r) {
            int m = mbase + i * 16 + q * 4 + r;
            float vv = acc[i][r];
            if (isPs) vv += bias[m];
            Cp[(size_t)m * 1024 + col] =
                __builtin_amdgcn_exp2f(vv * TWO_LOG2E);
        }
    }
}

// ------------------------------------------- fused tanh-dot + softmax
// block = (n, y-quad), 1024 threads (16 waves); thread t owns x = t and
// 4 y-rows. 4-term rcp sharing + f32x2 packing over y-pairs.
__global__ void __launch_bounds__(1024) attn_softmax(
    const float* __restrict__ Eph, const float* __restrict__ Eps,
    const float* __restrict__ v, float* __restrict__ out)
{
    int bid = blockIdx.x;            // 256 blocks = n(8) x yg(32)
    int n = bid >> 5, yg = bid & 31;
    int ny = n * 128 + yg * 4;       // 4 consecutive global rows
    const float* ph = Eph + (size_t)n * 131072;
    int t = threadIdx.x;             // x = t

    __shared__ float4 ps_s[128];     // Eps[a][ny..ny+3]
    __shared__ float4 v4_s[32];      // v[4a..4a+3]
    __shared__ float wred[4][16];
    __shared__ float VsumS;

    if (t < 128) ps_s[t] = *(const float4*)(Eps + (size_t)t * 1024 + ny);
    if (t >= 128 && t < 160) v4_s[t - 128] = *(const float4*)(v + (t - 128) * 4);
    if (t >= 960) {                  // last wave computes Vsum (disjoint)
        int l = t - 960;
        float vv = v[l] + v[l + 64];
        for (int m = 32; m; m >>= 1) vv += __shfl_xor(vv, m);
        if (l == 0) VsumS = vv;
    }
    __syncthreads();
    float Vsum = VsumS;

    // acc[0] = {acc_y0, acc_y1}, acc[1] = {acc_y2, acc_y3}
    f32x2 acc[2] = {{0.f, 0.f}, {0.f, 0.f}};
    const f32x2 one2 = {1.f, 1.f};
    #pragma unroll 2
    for (int a = 0; a < 128; a += 4) {
        float4 q0 = ps_s[a + 0], q1 = ps_s[a + 1];
        float4 q2 = ps_s[a + 2], q3 = ps_s[a + 3];
        float4 v4 = v4_s[a >> 2];
        float p0 = ph[(a + 0) * 1024 + t];
        float p1 = ph[(a + 1) * 1024 + t];
        float p2 = ph[(a + 2) * 1024 + t];
        float p3 = ph[(a + 3) * 1024 + t];
        // 4-term rational sum for a y-pair (packed), one x:
        // w_i = fma(EpsPair_i, ph_i, 1); pairwise merge; 1 rcp per comp.
        auto comb2 = [&](f32x2 ey0, f32x2 ey1, f32x2 ey2, f32x2 ey3,
                         f32x2& ac) {
            f32x2 w0 = FMA2(ey0, (f32x2)p0, one2);
            f32x2 w1 = FMA2(ey1, (f32x2)p1, one2);
            f32x2 w2 = FMA2(ey2, (f32x2)p2, one2);
            f32x2 w3 = FMA2(ey3, (f32x2)p3, one2);
            f32x2 d01 = w0 * w1, d23 = w2 * w3;
            f32x2 n01 = FMA2((f32x2)v4.y, w0, (f32x2)v4.x * w1);
            f32x2 n23 = FMA2((f32x2)v4.w, w2, (f32x2)v4.z * w3);
            f32x2 dd = d01 * d23;
            f32x2 nn = FMA2(n23, d01, n01 * d23);
            f32x2 r;
            r.x = __builtin_amdgcn_rcpf(dd.x);
            r.y = __builtin_amdgcn_rcpf(dd.y);
            ac = FMA2(nn, r, ac);
        };
        f32x2 a01_0 = {q0.x, q0.y}, a01_1 = {q1.x, q1.y};
        f32x2 a01_2 = {q2.x, q2.y}, a01_3 = {q3.x, q3.y};
        f32x2 a23_0 = {q0.z, q0.w}, a23_1 = {q1.z, q1.w};
        f32x2 a23_2 = {q2.z, q2.w}, a23_3 = {q3.z, q3.w};
        comb2(a01_0, a01_1, a01_2, a01_3, acc[0]);   // y0,y1
        comb2(a23_0, a23_1, a23_2, a23_3, acc[1]);   // y2,y3
    }
    float e[4];
    {
        f32x2 e01 = FMA2((f32x2)(-2.f), acc[0], (f32x2)Vsum);
        f32x2 e23 = FMA2((f32x2)(-2.f), acc[1], (f32x2)Vsum);
        e[0] = e01.x; e[1] = e01.y; e[2] = e23.x; e[3] = e23.y;
    }

    int lane = t & 63, wv = t >> 6;
    // block max per y (16 waves)
    #pragma unroll
    for (int y = 0; y < 4; ++y) {
        float mx = e[y];
        for (int m = 32; m; m >>= 1) mx = fmaxf(mx, __shfl_xor(mx, m));
        if (lane == 0) wred[y][wv] = mx;
    }
    __syncthreads();
    float mxv[4];
    #pragma unroll
    for (int y = 0; y < 4; ++y) {
        float mx = wred[y][0];
        #pragma unroll
        for (int i = 1; i < 16; ++i) mx = fmaxf(mx, wred[y][i]);
        mxv[y] = mx;
    }
    __syncthreads();
    // exp + block sum per y
    float sv[4];
    #pragma unroll
    for (int y = 0; y < 4; ++y) {
        sv[y] = __builtin_amdgcn_exp2f((e[y] - mxv[y]) * LOG2E);
        float sm = sv[y];
        for (int m = 32; m; m >>= 1) sm += __shfl_xor(sm, m);
        if (lane == 0) wred[y][wv] = sm;
    }
    __syncthreads();
    #pragma unroll
    for (int y = 0; y < 4; ++y) {
        float sm = 0.f;
        #pragma unroll
        for (int i = 0; i < 16; ++i) sm += wred[y][i];
        float r = __builtin_amdgcn_rcpf(sm);
        out[(size_t)(ny + y) * 1024 + t] = sv[y] * r;
    }
}

// ----------------------------------------------------------------- launcher
extern "C" void kernel_launch(void* const* d_in, const int* in_sizes, int n_in,
                              void* d_out, int out_size, void* d_ws, size_t ws_size,
                              hipStream_t stream) {
    const float* h  = (const float*)d_in[0];
    const float* s  = (const float*)d_in[1];
    const float* Wh = (const float*)d_in[2];
    const float* Ws = (const float*)d_in[3];
    const float* b  = (const float*)d_in[4];
    const float* v  = (const float*)d_in[5];
    float* out = (float*)d_out;

    char* ws = (char*)d_ws;
    float*  Eph = (float*)ws;                                  // 4 MB
    float*  Eps = (float*)(ws + (4u << 20));                   // 512 KB
    __bf16* WhT = (__bf16*)(ws + (4u << 20) + (512u << 10));   // 128 KB
    __bf16* WsT = WhT + (size_t)128 * 512;                     // 256 KB

    transpose_cast<<<24, 256, 0, stream>>>(Wh, Ws, WhT, WsT);
    gemm_fused<<<288, 256, 0, stream>>>(WhT, WsT, h, s, Eph, Eps, b);
    attn_softmax<<<256, 1024, 0, stream>>>(Eph, Eps, v, out);
}